// Round 7
// baseline (215.581 us; speedup 1.0000x reference)
//
#include <hip/hip_runtime.h>

#define BATCH 2
#define L_SEQ 2048
#define DI 2048
#define NROW (BATCH * L_SEQ)   // 4096
#define E_DIM 96
#define RNK 64                 // DT_RANK
#define NST 16                 // D_STATE
#define NCH 64                 // chunks
#define CL 32                  // chunk length
#define SPLITK 16              // K1 split-K factor
#define KSL (DI / SPLITK)      // 128 k per split

// ---------------- workspace layout (floats) ----------------
// xdbl  : [NROW][96]                               393216
// partials : [SPLITK][NROW][96]  6291456  (K1 -> reduce, then dead)
//   hloc : [B][NCH][NST][DI]     4194304  (overlays partials; C -> S2)
//   dsum : [B][NCH][DI]           262144  (overlays partials; C -> S2)
// hent  : [B][NCH][NST][DI]      4194304  (S2 -> S3)
//   WdtT : [RNK][DI]              131072  (overlays hent head; K1b -> C, dead before S2)
#define WS_XDBL 0
#define WS_PART 393216
#define WS_HLOC 393216
#define WS_DSUM (393216 + 4194304)
#define WS_HENT (393216 + 6291456)
#define WS_WDTT (393216 + 6291456)   // proven overlap (round 4): C reads before S2 writes

__device__ __forceinline__ float softplusf(float z) {
    return fmaxf(z, 0.f) + __logf(1.f + __expf(-fabsf(z)));
}

// raw barrier: LDS-visibility only (lgkmcnt), does NOT drain vmcnt.
__device__ __forceinline__ void barrier_lds() {
    asm volatile("s_waitcnt lgkmcnt(0)" ::: "memory");
    __builtin_amdgcn_s_barrier();
}

// ===== K1a: partial[s] = x[:, ksl] @ W^T slice =====
// 512 threads, tile M=128 x N=96, k-step 32, KSL=128. grid (32, 16).
// M=128 halves W HBM traffic vs M=64 (24MB total).
__global__ __launch_bounds__(512) void gemm_xproj_part(const float* __restrict__ x,
                                                       const float* __restrict__ Wx,
                                                       float* __restrict__ part) {
    __shared__ float xs[32][132];   // [k][row 0..127], pitch 528B (16B aligned)
    __shared__ float wsh[32][100];  // [k][e]
    const int tid = threadIdx.x;
    const int r0 = blockIdx.x * 128;
    const int kbase0 = blockIdx.y * KSL;
    const int rg = tid >> 4;   // 32 groups of 4 rows
    const int cg = tid & 15;   // 16 groups of 6 cols

    float acc[4][6];
#pragma unroll
    for (int i = 0; i < 4; i++)
#pragma unroll
        for (int j = 0; j < 6; j++) acc[i][j] = 0.f;

    for (int kt = 0; kt < KSL / 32; kt++) {
        const int kb = kbase0 + kt * 32;
        // x tile: 128 rows x 32 k = 1024 f4, 2/thread
#pragma unroll
        for (int rep = 0; rep < 2; rep++) {
            int i = rep * 512 + tid;
            int row = i >> 3, kq = i & 7;
            float4 v = *(const float4*)&x[(long)(r0 + row) * DI + kb + kq * 4];
            xs[kq * 4 + 0][row] = v.x;
            xs[kq * 4 + 1][row] = v.y;
            xs[kq * 4 + 2][row] = v.z;
            xs[kq * 4 + 3][row] = v.w;
        }
        // w tile: 96 e x 32 k = 768 f4: one full round + one half round
        {
            int e = tid >> 3, kq = tid & 7;
            float4 v = *(const float4*)&Wx[(long)e * DI + kb + kq * 4];
            wsh[kq * 4 + 0][e] = v.x;
            wsh[kq * 4 + 1][e] = v.y;
            wsh[kq * 4 + 2][e] = v.z;
            wsh[kq * 4 + 3][e] = v.w;
        }
        if (tid < 256) {
            int i = 512 + tid;
            int e = i >> 3, kq = i & 7;
            float4 v = *(const float4*)&Wx[(long)e * DI + kb + kq * 4];
            wsh[kq * 4 + 0][e] = v.x;
            wsh[kq * 4 + 1][e] = v.y;
            wsh[kq * 4 + 2][e] = v.z;
            wsh[kq * 4 + 3][e] = v.w;
        }
        __syncthreads();
#pragma unroll 8
        for (int k = 0; k < 32; k++) {
            float4 xa = *(const float4*)&xs[k][rg * 4];   // b128 (16B aligned)
            float xr[4] = {xa.x, xa.y, xa.z, xa.w};
            float wr[6];
#pragma unroll
            for (int j = 0; j < 6; j++) wr[j] = wsh[k][cg * 6 + j];
#pragma unroll
            for (int i = 0; i < 4; i++)
#pragma unroll
                for (int j = 0; j < 6; j++) acc[i][j] = fmaf(xr[i], wr[j], acc[i][j]);
        }
        __syncthreads();
    }
    const long sbase = (long)blockIdx.y * NROW * E_DIM;
#pragma unroll
    for (int i = 0; i < 4; i++) {
        long rowb = sbase + (long)(r0 + rg * 4 + i) * E_DIM + cg * 6;
#pragma unroll
        for (int j = 0; j < 6; j++) part[rowb + j] = acc[i][j];
    }
}

// ===== K1b: xdbl = sum over splits + WdtT transpose (proven) =====
__global__ __launch_bounds__(256) void xproj_reduce_wt(const float* __restrict__ part,
                                                       float* __restrict__ xdbl,
                                                       const float* __restrict__ Wdt,
                                                       float* __restrict__ wdtT) {
    if (blockIdx.x < 384) {
        const int i4 = blockIdx.x * 256 + threadIdx.x;
        const float4* p4 = (const float4*)part;
        float4 s = p4[i4];
#pragma unroll
        for (int sp = 1; sp < SPLITK; sp++) {
            float4 v = p4[(long)sp * (NROW * E_DIM / 4) + i4];
            s.x += v.x; s.y += v.y; s.z += v.z; s.w += v.w;
        }
        ((float4*)xdbl)[i4] = s;
    } else {
        const int t = (blockIdx.x - 384) * 256 + threadIdx.x;
        const int base = t * 4;
        const int r = base >> 11;
        const int d4 = base & (DI - 1);
        float4 o;
        o.x = Wdt[(long)(d4 + 0) * RNK + r];
        o.y = Wdt[(long)(d4 + 1) * RNK + r];
        o.z = Wdt[(long)(d4 + 2) * RNK + r];
        o.w = Wdt[(long)(d4 + 3) * RNK + r];
        *(float4*)&wdtT[base] = o;
    }
}

// ===== C: fused delta-GEMM + chunk-local scan, n-split for occupancy =====
// 512 threads, grid (8, 64, 2) = 1024 blocks. 27.6KB LDS. Each thread owns
// one d-column x 8 of 16 states (half = tid>>8). x is a pipelined demand
// stream (8-deep) instead of a 32-reg prefetch -> VGPR low -> 24-32 waves/CU.
#define PWT 256   // wt pitch (unpadded; b128 full-row pattern is conflict-free)
#define PDC 36    // dlb pitch (16B-aligned rows)
__global__ __launch_bounds__(512, 6) void gemm_dt_scan(const float* __restrict__ x,
                                                       const float* __restrict__ xdbl,
                                                       const float* __restrict__ wdtT,
                                                       const float* __restrict__ b_dt,
                                                       const float* __restrict__ A_log,
                                                       float* __restrict__ delta,
                                                       float* __restrict__ hloc,
                                                       float* __restrict__ dsumb) {
    __shared__ float region[16 * PWT + RNK * PDC];   // 6400 fl = 25.6KB
    __shared__ float bsm[CL * NST];                  // 2KB
    float* wt  = region;              // [16][256] per-16k-round Wdt^T
    float* dlb = region + 16 * PWT;   // [64][36] full-K dlt (staged once)
    float* dtt = region;              // [16][256] delta transpose (overlay after GEMM)

    const int tid = threadIdx.x;
    const int d0 = blockIdx.x * 256;
    const int c = blockIdx.y;
    const int b = blockIdx.z;
    const int row0 = b * L_SEQ + c * CL;
    const int dcol = tid & 255;
    const int d = d0 + dcol;
    const int half = tid >> 8;     // n-states half*8 .. half*8+7
    const int rg = tid >> 6;       // wave id = GEMM row-group (4 rows each)
    const int cg = tid & 63;       // 64 col-groups of 4

#define STAGE_WT(RND) { \
    _Pragma("unroll") \
    for (int rep = 0; rep < 2; rep++) { \
        int i = rep * 512 + tid; int k = i >> 6, c4 = i & 63; \
        *(float4*)&wt[k * PWT + c4 * 4] = \
            *(const float4*)&wdtT[(long)((RND) * 16 + k) * DI + d0 + c4 * 4]; } }

    // ---- issue staging (oldest in vmcnt FIFO), then params ----
    STAGE_WT(0);
    // dlt full-K: 32 rows x 64 k = 512 f4, 1/thread
    {
        int r = tid >> 4, kq = tid & 15;
        float4 v = *(const float4*)&xdbl[(long)(row0 + r) * E_DIM + kq * 4];
        dlb[(kq * 4 + 0) * PDC + r] = v.x;
        dlb[(kq * 4 + 1) * PDC + r] = v.y;
        dlb[(kq * 4 + 2) * PDC + r] = v.z;
        dlb[(kq * 4 + 3) * PDC + r] = v.w;
    }
    // B tile (chunk rows, xdbl cols 64..79)
    if (tid < 128) {
        int r = tid >> 2, q = tid & 3;
        ((float4*)bsm)[tid] = *(const float4*)&xdbl[(long)(row0 + r) * E_DIM + 64 + q * 4];
    }
    float4 av0 = *(const float4*)&A_log[(long)d * NST + 0];
    float4 av1 = *(const float4*)&A_log[(long)d * NST + 4];
    float4 av2 = *(const float4*)&A_log[(long)d * NST + 8];
    float4 av3 = *(const float4*)&A_log[(long)d * NST + 12];
    float4 bb  = *(const float4*)&b_dt[d0 + cg * 4];

    float acc[4][4];
#pragma unroll
    for (int i = 0; i < 4; i++)
#pragma unroll
        for (int j = 0; j < 4; j++) acc[i][j] = 0.f;

    barrier_lds();
#pragma unroll
    for (int rnd = 0; rnd < 4; rnd++) {
#pragma unroll 8
        for (int k = 0; k < 16; k++) {
            float4 xa = *(const float4*)&dlb[(rnd * 16 + k) * PDC + rg * 4];  // bcast
            float4 w4 = *(const float4*)&wt[k * PWT + cg * 4];
            float xr[4] = {xa.x, xa.y, xa.z, xa.w};
#pragma unroll
            for (int i = 0; i < 4; i++) {
                acc[i][0] = fmaf(xr[i], w4.x, acc[i][0]);
                acc[i][1] = fmaf(xr[i], w4.y, acc[i][1]);
                acc[i][2] = fmaf(xr[i], w4.z, acc[i][2]);
                acc[i][3] = fmaf(xr[i], w4.w, acc[i][3]);
            }
        }
        barrier_lds();                 // all reads of this wt round done
        if (rnd < 3) {
            STAGE_WT(rnd + 1);         // counted vmcnt wait (compiler)
            barrier_lds();             // staged round visible
        }
    }

    // ---- epilogue: softplus in place, delta global store (fire-and-forget) ----
#pragma unroll
    for (int i = 0; i < 4; i++) {
        acc[i][0] = softplusf(acc[i][0] + bb.x);
        acc[i][1] = softplusf(acc[i][1] + bb.y);
        acc[i][2] = softplusf(acc[i][2] + bb.z);
        acc[i][3] = softplusf(acc[i][3] + bb.w);
        float4 o = {acc[i][0], acc[i][1], acc[i][2], acc[i][3]};
        *(float4*)&delta[(long)(row0 + rg * 4 + i) * DI + d0 + cg * 4] = o;
    }

    // ---- A params (fast iff A[n] == (n+1)*A0) ----
    float a16[16];
    a16[0] = -__expf(av0.x); a16[1] = -__expf(av0.y);
    a16[2] = -__expf(av0.z); a16[3] = -__expf(av0.w);
    a16[4] = -__expf(av1.x); a16[5] = -__expf(av1.y);
    a16[6] = -__expf(av1.z); a16[7] = -__expf(av1.w);
    a16[8] = -__expf(av2.x); a16[9] = -__expf(av2.y);
    a16[10] = -__expf(av2.z); a16[11] = -__expf(av2.w);
    a16[12] = -__expf(av3.x); a16[13] = -__expf(av3.y);
    a16[14] = -__expf(av3.z); a16[15] = -__expf(av3.w);
    const float A0 = a16[0];
    bool fast = true;
#pragma unroll
    for (int n = 1; n < 16; n++)
        fast = fast && (fabsf(a16[n] - (float)(n + 1) * A0) <= 1e-4f * (float)(n + 1));
    const float A0f = A0 * (float)(8 * half + 1);
    float g[8];
#pragma unroll
    for (int j = 0; j < 8; j++) g[j] = half ? a16[8 + j] : a16[j];   // static idx both

#define LOADX(XA, LL0) { _Pragma("unroll") \
    for (int j = 0; j < 8; j++) XA[j] = x[(long)(row0 + (LL0) + j) * DI + d]; }
#define COPYX { _Pragma("unroll") for (int j = 0; j < 8; j++) xcur[j] = xnxt[j]; }

#define SCAN_BATCH(LL0, SL0, XA) \
    if (fast) { \
        _Pragma("unroll") \
        for (int j = 0; j < 8; j++) { \
            float dc = dtt[((SL0) + j) * 256 + dcol]; \
            float du = dc * XA[j]; \
            float4 v0 = *(const float4*)&bsm[((LL0) + j) * NST + half * 8]; \
            float4 v1 = *(const float4*)&bsm[((LL0) + j) * NST + half * 8 + 4]; \
            float p1 = __expf(dc * A0); \
            float e  = __expf(dc * A0f); \
            h[0] = fmaf(e, h[0], du * v0.x); e *= p1; \
            h[1] = fmaf(e, h[1], du * v0.y); e *= p1; \
            h[2] = fmaf(e, h[2], du * v0.z); e *= p1; \
            h[3] = fmaf(e, h[3], du * v0.w); e *= p1; \
            h[4] = fmaf(e, h[4], du * v1.x); e *= p1; \
            h[5] = fmaf(e, h[5], du * v1.y); e *= p1; \
            h[6] = fmaf(e, h[6], du * v1.z); e *= p1; \
            h[7] = fmaf(e, h[7], du * v1.w); \
            dsum += dc; \
        } \
    } else { \
        _Pragma("unroll") \
        for (int j = 0; j < 8; j++) { \
            float dc = dtt[((SL0) + j) * 256 + dcol]; \
            float du = dc * XA[j]; \
            float4 v0 = *(const float4*)&bsm[((LL0) + j) * NST + half * 8]; \
            float4 v1 = *(const float4*)&bsm[((LL0) + j) * NST + half * 8 + 4]; \
            h[0] = fmaf(__expf(dc * g[0]), h[0], du * v0.x); \
            h[1] = fmaf(__expf(dc * g[1]), h[1], du * v0.y); \
            h[2] = fmaf(__expf(dc * g[2]), h[2], du * v0.z); \
            h[3] = fmaf(__expf(dc * g[3]), h[3], du * v0.w); \
            h[4] = fmaf(__expf(dc * g[4]), h[4], du * v1.x); \
            h[5] = fmaf(__expf(dc * g[5]), h[5], du * v1.y); \
            h[6] = fmaf(__expf(dc * g[6]), h[6], du * v1.z); \
            h[7] = fmaf(__expf(dc * g[7]), h[7], du * v1.w); \
            dsum += dc; \
        } \
    }

    // ---- scan: transpose delta through dtt16 in 2 rounds, interleaved ----
    float xcur[8], xnxt[8];
    LOADX(xcur, 0);
    if (rg < 4) {                      // waves 0-3 own rows 0..15 (wave-uniform)
#pragma unroll
        for (int i = 0; i < 4; i++) {
            float4 o = {acc[i][0], acc[i][1], acc[i][2], acc[i][3]};
            *(float4*)&dtt[(rg * 4 + i) * 256 + cg * 4] = o;
        }
    }
    barrier_lds();                     // dtt rows 0..15 visible

    float h[8];
#pragma unroll
    for (int j = 0; j < 8; j++) h[j] = 0.f;
    float dsum = 0.f;

    LOADX(xnxt, 8);
    SCAN_BATCH(0, 0, xcur);
    COPYX;
    LOADX(xnxt, 16);
    SCAN_BATCH(8, 8, xcur);
    COPYX;
    barrier_lds();                     // all waves done reading dtt rows 0..15
    if (rg >= 4) {                     // waves 4-7 own rows 16..31 -> slots 0..15
#pragma unroll
        for (int i = 0; i < 4; i++) {
            float4 o = {acc[i][0], acc[i][1], acc[i][2], acc[i][3]};
            *(float4*)&dtt[((rg - 4) * 4 + i) * 256 + cg * 4] = o;
        }
    }
    barrier_lds();                     // dtt rows 16..31 visible
    LOADX(xnxt, 24);
    SCAN_BATCH(16, 0, xcur);
    COPYX;
    SCAN_BATCH(24, 8, xcur);

    // hloc layout [b][c][n][d]: coalesced
    const long cb = (long)(b * NCH + c);
#pragma unroll
    for (int j = 0; j < 8; j++)
        hloc[(cb * NST + half * 8 + j) * DI + d] = h[j];
    if (half == 0) dsumb[cb * DI + d] = dsum;
}

// power chain for S3: e_[n] = p1^(n+1), 1 exp + 15 mul
#define PCHAIN_E16(DCV) \
    float p1 = __expf((DCV) * A0); \
    float p2 = p1 * p1, p3 = p2 * p1, p4 = p2 * p2, p5 = p4 * p1; \
    float p6 = p3 * p3, p7 = p4 * p3, p8 = p4 * p4; \
    float e_[16] = {p1, p2, p3, p4, p5, p6, p7, p8, \
                    p8 * p1, p5 * p5, p8 * p3, p6 * p6, \
                    p8 * p5, p7 * p7, p8 * p7, p8 * p8};

// ===== S2: prefix over chunks -> entry states (proven round-4) =====
__global__ __launch_bounds__(256, 1) void scan_prefix(const float* __restrict__ A_log,
                                                      const float* __restrict__ hloc,
                                                      const float* __restrict__ dsumb,
                                                      float* __restrict__ hent) {
    const int gidx = blockIdx.x * 256 + threadIdx.x;
    const int d = gidx & (DI - 1);
    const int n = (gidx >> 11) & 15;
    const int b = gidx >> 15;
    const float An = -__expf(A_log[(long)d * NST + n]);
    float hl[NCH], dsv[NCH];
#pragma unroll
    for (int cc = 0; cc < NCH; cc++) {
        hl[cc]  = hloc[((long)(b * NCH + cc) * NST + n) * DI + d];
        dsv[cc] = dsumb[(long)(b * NCH + cc) * DI + d];
    }
    float e[NCH];
#pragma unroll
    for (int cc = 0; cc < NCH; cc++) e[cc] = __expf(An * dsv[cc]);
    float hc = 0.f;
#pragma unroll
    for (int cc = 0; cc < NCH; cc++) {
        hent[((long)(b * NCH + cc) * NST + n) * DI + d] = hc;
        hc = fmaf(e[cc], hc, hl[cc]);
    }
}

// ===== S3: output pass — columns prefetched to registers (proven round-4) =====
__global__ __launch_bounds__(256) void scan_out(const float* __restrict__ x,
                                                const float* __restrict__ xdbl,
                                                const float* __restrict__ A_log,
                                                const float* __restrict__ Dp,
                                                const float* __restrict__ hent,
                                                float* __restrict__ out) {
    __shared__ float bsm[CL * NST];
    __shared__ float csm[CL * NST];
    const int tid = threadIdx.x;
    const int d0 = blockIdx.x * 256;
    const int c = blockIdx.y;
    const int b = blockIdx.z;
    const int row0 = b * L_SEQ + c * CL;
    const int d = d0 + tid;

    {
        int i = tid & 127, r = i >> 2, q = i & 3;
        float4 v = *(const float4*)&xdbl[(long)(row0 + r) * E_DIM + 64 + ((tid >> 7) << 4) + q * 4];
        if (tid < 128) ((float4*)bsm)[i] = v;
        else           ((float4*)csm)[i] = v;
    }
    __syncthreads();

    float4 av[4];
#pragma unroll
    for (int q = 0; q < 4; q++)
        av[q] = *(const float4*)&A_log[(long)d * NST + q * 4];
    const long cb = (long)(b * NCH + c);
    float hv[16];
#pragma unroll
    for (int n = 0; n < 16; n++)
        hv[n] = hent[(cb * NST + n) * DI + d];
    const float Dd = Dp[d];

    float dv[CL], xvv[CL];
#pragma unroll
    for (int ll = 0; ll < CL; ll++) {
        dv[ll] = out[(long)(row0 + ll) * DI + d];
        xvv[ll] = x[(long)(row0 + ll) * DI + d];
    }

    float A[16];
#pragma unroll
    for (int q = 0; q < 4; q++) {
        A[q * 4 + 0] = -__expf(av[q].x);
        A[q * 4 + 1] = -__expf(av[q].y);
        A[q * 4 + 2] = -__expf(av[q].z);
        A[q * 4 + 3] = -__expf(av[q].w);
    }
    const float A0 = A[0];
    bool fast = true;
#pragma unroll
    for (int n = 1; n < 16; n++)
        fast = fast && (fabsf(A[n] - (float)(n + 1) * A0) <= 1e-4f * (float)(n + 1));
    float h[16];
#pragma unroll
    for (int n = 0; n < 16; n++) h[n] = hv[n];

    long idx = (long)row0 * DI + d;
    if (fast) {
        for (int ll = 0; ll < CL; ll++) {
            float dc = dv[ll];
            float xc = xvv[ll];
            float du = dc * xc;
            PCHAIN_E16(dc);
            float y = 0.f;
#pragma unroll
            for (int q = 0; q < 4; q++) {
                float4 v = *(const float4*)&bsm[ll * NST + q * 4];
                float4 w = *(const float4*)&csm[ll * NST + q * 4];
                h[q * 4 + 0] = fmaf(e_[q * 4 + 0], h[q * 4 + 0], du * v.x);
                h[q * 4 + 1] = fmaf(e_[q * 4 + 1], h[q * 4 + 1], du * v.y);
                h[q * 4 + 2] = fmaf(e_[q * 4 + 2], h[q * 4 + 2], du * v.z);
                h[q * 4 + 3] = fmaf(e_[q * 4 + 3], h[q * 4 + 3], du * v.w);
                y = fmaf(h[q * 4 + 0], w.x, y);
                y = fmaf(h[q * 4 + 1], w.y, y);
                y = fmaf(h[q * 4 + 2], w.z, y);
                y = fmaf(h[q * 4 + 3], w.w, y);
            }
            out[idx] = fmaf(xc, Dd, y);
            idx += DI;
        }
    } else {
        for (int ll = 0; ll < CL; ll++) {
            float dc = dv[ll];
            float xc = xvv[ll];
            float du = dc * xc;
            float y = 0.f;
#pragma unroll
            for (int q = 0; q < 4; q++) {
                float4 v = *(const float4*)&bsm[ll * NST + q * 4];
                float4 w = *(const float4*)&csm[ll * NST + q * 4];
                h[q * 4 + 0] = fmaf(__expf(dc * A[q * 4 + 0]), h[q * 4 + 0], du * v.x);
                h[q * 4 + 1] = fmaf(__expf(dc * A[q * 4 + 1]), h[q * 4 + 1], du * v.y);
                h[q * 4 + 2] = fmaf(__expf(dc * A[q * 4 + 2]), h[q * 4 + 2], du * v.z);
                h[q * 4 + 3] = fmaf(__expf(dc * A[q * 4 + 3]), h[q * 4 + 3], du * v.w);
                y = fmaf(h[q * 4 + 0], w.x, y);
                y = fmaf(h[q * 4 + 1], w.y, y);
                y = fmaf(h[q * 4 + 2], w.z, y);
                y = fmaf(h[q * 4 + 3], w.w, y);
            }
            out[idx] = fmaf(xc, Dd, y);
            idx += DI;
        }
    }
}

extern "C" void kernel_launch(void* const* d_in, const int* in_sizes, int n_in,
                              void* d_out, int out_size, void* d_ws, size_t ws_size,
                              hipStream_t stream) {
    const float* x    = (const float*)d_in[0];
    const float* Wx   = (const float*)d_in[1];
    const float* Wdt  = (const float*)d_in[2];
    const float* bdt  = (const float*)d_in[3];
    const float* Alog = (const float*)d_in[4];
    const float* Dp   = (const float*)d_in[5];
    float* out = (float*)d_out;
    float* ws = (float*)d_ws;
    float* xdbl  = ws + WS_XDBL;
    float* partb = ws + WS_PART;
    float* hloc  = ws + WS_HLOC;
    float* dsumb = ws + WS_DSUM;
    float* hent  = ws + WS_HENT;
    float* wdtT  = ws + WS_WDTT;   // overlays hent head (dead before S2 writes)

    gemm_xproj_part<<<dim3(NROW / 128, SPLITK), 512, 0, stream>>>(x, Wx, partb);
    xproj_reduce_wt<<<dim3(512), 256, 0, stream>>>(partb, xdbl, Wdt, wdtT);
    gemm_dt_scan<<<dim3(DI / 256, NCH, BATCH), 512, 0, stream>>>(x, xdbl, wdtT, bdt, Alog,
                                                                 out, hloc, dsumb);
    scan_prefix<<<dim3(BATCH * DI * NST / 256), 256, 0, stream>>>(Alog, hloc, dsumb, hent);
    scan_out<<<dim3(DI / 256, NCH, BATCH), 256, 0, stream>>>(x, xdbl, Alog, Dp, hent, out);
}

// Round 8
// 208.768 us; speedup vs baseline: 1.0326x; 1.0326x over previous
//
#include <hip/hip_runtime.h>

#define BATCH 2
#define L_SEQ 2048
#define DI 2048
#define NROW (BATCH * L_SEQ)   // 4096
#define E_DIM 96
#define RNK 64                 // DT_RANK
#define NST 16                 // D_STATE
#define NCH 32                 // chunks (length 64 each)
#define CL 32                  // subtile length (2 subtiles per chunk)
#define SPLITK 16              // K1 split-K factor
#define KSL (DI / SPLITK)      // 128 k per split

// ---------------- workspace layout (floats) ----------------
// xdbl     : [NROW][96]              @0        (393216)
// partials : [SPLITK][NROW][96]      @393216   (6291456), dead after K1b
//   hloc   : [B][32][NST][DI]        @393216   (2097152)  C -> S2 (overlay)
//   dsum   : [B][32][DI]             @2490368  (131072)   C -> S2 (overlay)
// hent     : [B][32][NST][DI]        @6684672  (2097152)  S2 -> S3
// wdtT     : [RNK][DI]               @8781824  (131072)   K1b -> C (no overlay)
#define WS_XDBL 0
#define WS_PART 393216
#define WS_HLOC 393216
#define WS_DSUM (393216 + 2097152)
#define WS_HENT (393216 + 6291456)
#define WS_WDTT (WS_HENT + 2097152)

__device__ __forceinline__ float softplusf(float z) {
    return fmaxf(z, 0.f) + __logf(1.f + __expf(-fabsf(z)));
}

// raw barrier: LDS-visibility only (lgkmcnt), does NOT drain vmcnt.
__device__ __forceinline__ void barrier_lds() {
    asm volatile("s_waitcnt lgkmcnt(0)" ::: "memory");
    __builtin_amdgcn_s_barrier();
}

// power chain: e_[n] = p1^(n+1), 1 exp + 15 mul (valid when A[n]==(n+1)*A0)
#define PCHAIN_E16(DCV) \
    float p1 = __expf((DCV) * A0); \
    float p2 = p1 * p1, p3 = p2 * p1, p4 = p2 * p2, p5 = p4 * p1; \
    float p6 = p3 * p3, p7 = p4 * p3, p8 = p4 * p4; \
    float e_[16] = {p1, p2, p3, p4, p5, p6, p7, p8, \
                    p8 * p1, p5 * p5, p8 * p3, p6 * p6, \
                    p8 * p5, p7 * p7, p8 * p7, p8 * p8};

// ===== K1a: partial[s] = x[:, ksl] @ W^T slice =====
// 512 threads, tile M=128 x N=96, k-step 32, KSL=128. grid (32, 16).
// (round-7 version: M=128 halves W HBM traffic; rode along in a passing run)
__global__ __launch_bounds__(512) void gemm_xproj_part(const float* __restrict__ x,
                                                       const float* __restrict__ Wx,
                                                       float* __restrict__ part) {
    __shared__ float xs[32][132];   // [k][row 0..127], pitch 528B (16B aligned)
    __shared__ float wsh[32][100];  // [k][e]
    const int tid = threadIdx.x;
    const int r0 = blockIdx.x * 128;
    const int kbase0 = blockIdx.y * KSL;
    const int rg = tid >> 4;   // 32 groups of 4 rows
    const int cg = tid & 15;   // 16 groups of 6 cols

    float acc[4][6];
#pragma unroll
    for (int i = 0; i < 4; i++)
#pragma unroll
        for (int j = 0; j < 6; j++) acc[i][j] = 0.f;

    for (int kt = 0; kt < KSL / 32; kt++) {
        const int kb = kbase0 + kt * 32;
#pragma unroll
        for (int rep = 0; rep < 2; rep++) {
            int i = rep * 512 + tid;
            int row = i >> 3, kq = i & 7;
            float4 v = *(const float4*)&x[(long)(r0 + row) * DI + kb + kq * 4];
            xs[kq * 4 + 0][row] = v.x;
            xs[kq * 4 + 1][row] = v.y;
            xs[kq * 4 + 2][row] = v.z;
            xs[kq * 4 + 3][row] = v.w;
        }
        {
            int e = tid >> 3, kq = tid & 7;
            float4 v = *(const float4*)&Wx[(long)e * DI + kb + kq * 4];
            wsh[kq * 4 + 0][e] = v.x;
            wsh[kq * 4 + 1][e] = v.y;
            wsh[kq * 4 + 2][e] = v.z;
            wsh[kq * 4 + 3][e] = v.w;
        }
        if (tid < 256) {
            int i = 512 + tid;
            int e = i >> 3, kq = i & 7;
            float4 v = *(const float4*)&Wx[(long)e * DI + kb + kq * 4];
            wsh[kq * 4 + 0][e] = v.x;
            wsh[kq * 4 + 1][e] = v.y;
            wsh[kq * 4 + 2][e] = v.z;
            wsh[kq * 4 + 3][e] = v.w;
        }
        __syncthreads();
#pragma unroll 8
        for (int k = 0; k < 32; k++) {
            float4 xa = *(const float4*)&xs[k][rg * 4];   // b128 (16B aligned)
            float xr[4] = {xa.x, xa.y, xa.z, xa.w};
            float wr[6];
#pragma unroll
            for (int j = 0; j < 6; j++) wr[j] = wsh[k][cg * 6 + j];
#pragma unroll
            for (int i = 0; i < 4; i++)
#pragma unroll
                for (int j = 0; j < 6; j++) acc[i][j] = fmaf(xr[i], wr[j], acc[i][j]);
        }
        __syncthreads();
    }
    const long sbase = (long)blockIdx.y * NROW * E_DIM;
#pragma unroll
    for (int i = 0; i < 4; i++) {
        long rowb = sbase + (long)(r0 + rg * 4 + i) * E_DIM + cg * 6;
#pragma unroll
        for (int j = 0; j < 6; j++) part[rowb + j] = acc[i][j];
    }
}

// ===== K1b: xdbl = sum over splits + WdtT transpose (proven) =====
__global__ __launch_bounds__(256) void xproj_reduce_wt(const float* __restrict__ part,
                                                       float* __restrict__ xdbl,
                                                       const float* __restrict__ Wdt,
                                                       float* __restrict__ wdtT) {
    if (blockIdx.x < 384) {
        const int i4 = blockIdx.x * 256 + threadIdx.x;
        const float4* p4 = (const float4*)part;
        float4 s = p4[i4];
#pragma unroll
        for (int sp = 1; sp < SPLITK; sp++) {
            float4 v = p4[(long)sp * (NROW * E_DIM / 4) + i4];
            s.x += v.x; s.y += v.y; s.z += v.z; s.w += v.w;
        }
        ((float4*)xdbl)[i4] = s;
    } else {
        const int t = (blockIdx.x - 384) * 256 + threadIdx.x;
        const int base = t * 4;
        const int r = base >> 11;
        const int d4 = base & (DI - 1);
        float4 o;
        o.x = Wdt[(long)(d4 + 0) * RNK + r];
        o.y = Wdt[(long)(d4 + 1) * RNK + r];
        o.z = Wdt[(long)(d4 + 2) * RNK + r];
        o.w = Wdt[(long)(d4 + 3) * RNK + r];
        *(float4*)&wdtT[base] = o;
    }
}

// ===== C: fused delta-GEMM + chunk-local scan, 64-row chunk = 2 subtiles =====
// 256 threads, grid (8, 32, 2) = 512 blocks. LDS 39424 B -> 4 blocks/CU.
// Round-4-proven body per subtile; h[16] carried across subtiles in registers.
#define PWT 256   // wt pitch (full-row-consecutive access: no pad needed)
#define PD 36     // dlb pitch (16B-aligned rows)
__global__ __launch_bounds__(256) void gemm_dt_scan(const float* __restrict__ x,
                                                    const float* __restrict__ xdbl,
                                                    const float* __restrict__ wdtT,
                                                    const float* __restrict__ b_dt,
                                                    const float* __restrict__ A_log,
                                                    float* __restrict__ delta,
                                                    float* __restrict__ hloc,
                                                    float* __restrict__ dsumb) {
    __shared__ float region[32 * PWT + 32 * PD];   // 9344 fl = 37376 B
    __shared__ float bsm[CL * NST];                // 2 KB (per-subtile B rows)
    float* wt  = region;               // [32][256] Wdt^T staging [k][col]
    float* dlb = region + 32 * PWT;    // [32][36]  dlt staging [k][row]
    float* dtt = region;               // [32][256] delta tile (overlay after GEMM)

    const int tid = threadIdx.x;
    const int d0 = blockIdx.x * 256;
    const int c = blockIdx.y;          // 0..31 (64-row chunks)
    const int b = blockIdx.z;
    const int row0 = b * L_SEQ + c * 64;
    const int d = d0 + tid;
    const int rg = tid >> 6;           // 4 groups of 8 rows (wave-uniform)
    const int cg = tid & 63;           // 64 groups of 4 cols

    float h[16];
#pragma unroll
    for (int n = 0; n < 16; n++) h[n] = 0.f;
    float dsum = 0.f;
    float A0 = 0.f; bool fast = false;
    float4 bb;
    float xv[CL]; float4 bsv; float4 av[4];

#pragma unroll
    for (int s = 0; s < 2; s++) {
        const int rowS = row0 + s * CL;
        if (s) barrier_lds();          // scan(s-1) done reading dtt/bsm
        float acc[8][4];
#pragma unroll
        for (int i = 0; i < 8; i++)
#pragma unroll
            for (int j = 0; j < 4; j++) acc[i][j] = 0.f;

#pragma unroll
        for (int kt = 0; kt < 2; kt++) {
            const int kb = kt * 32;
            // wt: 32k x 256 cols = 2048 f4, 8/thread (b128 writes, conflict-free)
#pragma unroll
            for (int rep = 0; rep < 8; rep++) {
                int i = rep * 256 + tid;
                int k = i >> 6, c4 = i & 63;
                *(float4*)&wt[k * PWT + c4 * 4] =
                    *(const float4*)&wdtT[(long)(kb + k) * DI + d0 + c4 * 4];
            }
            // dlt: 32 rows x 32 k = 256 f4, 1/thread (small transpose)
            {
                int r = tid >> 3, kq = tid & 7;
                float4 v = *(const float4*)&xdbl[(long)(rowS + r) * E_DIM + kb + kq * 4];
                dlb[(kq * 4 + 0) * PD + r] = v.x;
                dlb[(kq * 4 + 1) * PD + r] = v.y;
                dlb[(kq * 4 + 2) * PD + r] = v.z;
                dlb[(kq * 4 + 3) * PD + r] = v.w;
            }
            if (kt == 0) {
                // prefetches (after staging loads in vmcnt FIFO): land under GEMM
#pragma unroll
                for (int ll = 0; ll < CL; ll++)
                    xv[ll] = x[(long)(rowS + ll) * DI + d];
                if (tid < 128) {
                    int r = tid >> 2, q = tid & 3;
                    bsv = *(const float4*)&xdbl[(long)(rowS + r) * E_DIM + 64 + q * 4];
                }
                if (s == 0) {
#pragma unroll
                    for (int q = 0; q < 4; q++)
                        av[q] = *(const float4*)&A_log[(long)d * NST + q * 4];
                    bb = *(const float4*)&b_dt[d0 + cg * 4];
                }
            }
            barrier_lds();
#pragma unroll 8
            for (int k = 0; k < 32; k++) {
                float4 xa = *(const float4*)&dlb[k * PD + rg * 8];       // bcast
                float4 xb = *(const float4*)&dlb[k * PD + rg * 8 + 4];   // bcast
                float4 w4 = *(const float4*)&wt[k * PWT + cg * 4];       // 16B stride
                float xr[8] = {xa.x, xa.y, xa.z, xa.w, xb.x, xb.y, xb.z, xb.w};
#pragma unroll
                for (int i = 0; i < 8; i++) {
                    acc[i][0] = fmaf(xr[i], w4.x, acc[i][0]);
                    acc[i][1] = fmaf(xr[i], w4.y, acc[i][1]);
                    acc[i][2] = fmaf(xr[i], w4.z, acc[i][2]);
                    acc[i][3] = fmaf(xr[i], w4.w, acc[i][3]);
                }
            }
            barrier_lds();             // staging overwrite (kt=1) / dtt overlay safe
        }

        // epilogue: softplus -> delta (global, fire-and-forget) + dtt; bsm write
#pragma unroll
        for (int i = 0; i < 8; i++) {
            int r = rg * 8 + i;
            float4 o;
            o.x = softplusf(acc[i][0] + bb.x);
            o.y = softplusf(acc[i][1] + bb.y);
            o.z = softplusf(acc[i][2] + bb.z);
            o.w = softplusf(acc[i][3] + bb.w);
            *(float4*)&delta[(long)(rowS + r) * DI + d0 + cg * 4] = o;
            *(float4*)&dtt[r * 256 + cg * 4] = o;
        }
        if (tid < 128) {
            int r = tid >> 2, q = tid & 3;
            *(float4*)&bsm[r * NST + q * 4] = bsv;
        }
        if (s == 0) {
            float a16[16];
#pragma unroll
            for (int q = 0; q < 4; q++) {
                a16[q * 4 + 0] = -__expf(av[q].x);
                a16[q * 4 + 1] = -__expf(av[q].y);
                a16[q * 4 + 2] = -__expf(av[q].z);
                a16[q * 4 + 3] = -__expf(av[q].w);
            }
            A0 = a16[0];
            fast = true;
#pragma unroll
            for (int n = 1; n < 16; n++)
                fast = fast && (fabsf(a16[n] - (float)(n + 1) * A0) <= 1e-4f * (float)(n + 1));
        }
        barrier_lds();                 // dtt + bsm visible

        if (fast) {
            for (int ll = 0; ll < CL; ll++) {
                float dc = dtt[ll * 256 + tid];
                float du = dc * xv[ll];
                PCHAIN_E16(dc);
#pragma unroll
                for (int q = 0; q < 4; q++) {
                    float4 v = *(const float4*)&bsm[ll * NST + q * 4];   // bcast
                    h[q * 4 + 0] = fmaf(e_[q * 4 + 0], h[q * 4 + 0], du * v.x);
                    h[q * 4 + 1] = fmaf(e_[q * 4 + 1], h[q * 4 + 1], du * v.y);
                    h[q * 4 + 2] = fmaf(e_[q * 4 + 2], h[q * 4 + 2], du * v.z);
                    h[q * 4 + 3] = fmaf(e_[q * 4 + 3], h[q * 4 + 3], du * v.w);
                }
                dsum += dc;
            }
        } else {
            float Ag[16];
#pragma unroll
            for (int q = 0; q < 4; q++) {
                float4 t = *(const float4*)&A_log[(long)d * NST + q * 4];
                Ag[q * 4 + 0] = -__expf(t.x); Ag[q * 4 + 1] = -__expf(t.y);
                Ag[q * 4 + 2] = -__expf(t.z); Ag[q * 4 + 3] = -__expf(t.w);
            }
            for (int ll = 0; ll < CL; ll++) {
                float dc = dtt[ll * 256 + tid];
                float du = dc * xv[ll];
#pragma unroll
                for (int q = 0; q < 4; q++) {
                    float4 v = *(const float4*)&bsm[ll * NST + q * 4];
                    h[q * 4 + 0] = fmaf(__expf(dc * Ag[q * 4 + 0]), h[q * 4 + 0], du * v.x);
                    h[q * 4 + 1] = fmaf(__expf(dc * Ag[q * 4 + 1]), h[q * 4 + 1], du * v.y);
                    h[q * 4 + 2] = fmaf(__expf(dc * Ag[q * 4 + 2]), h[q * 4 + 2], du * v.z);
                    h[q * 4 + 3] = fmaf(__expf(dc * Ag[q * 4 + 3]), h[q * 4 + 3], du * v.w);
                }
                dsum += dc;
            }
        }
    }
    // hloc layout [b][c][n][d]: coalesced
    const long cb = (long)(b * NCH + c);
#pragma unroll
    for (int n = 0; n < 16; n++)
        hloc[(cb * NST + n) * DI + d] = h[n];
    dsumb[cb * DI + d] = dsum;
}

// ===== S2: prefix over 32 chunks -> entry states =====
__global__ __launch_bounds__(256, 1) void scan_prefix(const float* __restrict__ A_log,
                                                      const float* __restrict__ hloc,
                                                      const float* __restrict__ dsumb,
                                                      float* __restrict__ hent) {
    const int gidx = blockIdx.x * 256 + threadIdx.x;   // 65536 items, d fastest
    const int d = gidx & (DI - 1);
    const int n = (gidx >> 11) & 15;
    const int b = gidx >> 15;
    const float An = -__expf(A_log[(long)d * NST + n]);
    float hl[NCH], dsv[NCH];
#pragma unroll
    for (int cc = 0; cc < NCH; cc++) {
        hl[cc]  = hloc[((long)(b * NCH + cc) * NST + n) * DI + d];
        dsv[cc] = dsumb[(long)(b * NCH + cc) * DI + d];
    }
    float e[NCH];
#pragma unroll
    for (int cc = 0; cc < NCH; cc++) e[cc] = __expf(An * dsv[cc]);
    float hc = 0.f;
#pragma unroll
    for (int cc = 0; cc < NCH; cc++) {
        hent[((long)(b * NCH + cc) * NST + n) * DI + d] = hc;   // entry state
        hc = fmaf(e[cc], hc, hl[cc]);                           // exit state
    }
}

// ===== S3: output pass, 64-row chunk = 2 subtiles, columns in registers =====
__global__ __launch_bounds__(256) void scan_out(const float* __restrict__ x,
                                                const float* __restrict__ xdbl,
                                                const float* __restrict__ A_log,
                                                const float* __restrict__ Dp,
                                                const float* __restrict__ hent,
                                                float* __restrict__ out) {
    __shared__ float bsm[64 * NST];   // 4KB (whole chunk)
    __shared__ float csm[64 * NST];   // 4KB
    const int tid = threadIdx.x;
    const int d0 = blockIdx.x * 256;
    const int c = blockIdx.y;          // 0..31
    const int b = blockIdx.z;
    const int row0 = b * L_SEQ + c * 64;
    const int d = d0 + tid;

    {
        int r = tid >> 2, q = tid & 3;
        ((float4*)bsm)[tid] = *(const float4*)&xdbl[(long)(row0 + r) * E_DIM + 64 + q * 4];
        ((float4*)csm)[tid] = *(const float4*)&xdbl[(long)(row0 + r) * E_DIM + 80 + q * 4];
    }
    __syncthreads();   // only LDS staging outstanding; cheap drain

    // params first (oldest in vmcnt FIFO)
    float4 av[4];
#pragma unroll
    for (int q = 0; q < 4; q++)
        av[q] = *(const float4*)&A_log[(long)d * NST + q * 4];
    const long cb = (long)(b * NCH + c);
    float h[16];
#pragma unroll
    for (int n = 0; n < 16; n++)
        h[n] = hent[(cb * NST + n) * DI + d];
    const float Dd = Dp[d];

    float A[16];
#pragma unroll
    for (int q = 0; q < 4; q++) {
        A[q * 4 + 0] = -__expf(av[q].x);
        A[q * 4 + 1] = -__expf(av[q].y);
        A[q * 4 + 2] = -__expf(av[q].z);
        A[q * 4 + 3] = -__expf(av[q].w);
    }
    const float A0 = A[0];
    bool fast = true;
#pragma unroll
    for (int n = 1; n < 16; n++)
        fast = fast && (fabsf(A[n] - (float)(n + 1) * A0) <= 1e-4f * (float)(n + 1));

#pragma unroll
    for (int s = 0; s < 2; s++) {
        const int rowS = row0 + s * CL;
        float dv[CL], xvv[CL];
#pragma unroll
        for (int ll = 0; ll < CL; ll++) {
            dv[ll] = out[(long)(rowS + ll) * DI + d];
            xvv[ll] = x[(long)(rowS + ll) * DI + d];
        }
        long idx = (long)rowS * DI + d;
        if (fast) {
            for (int ll = 0; ll < CL; ll++) {
                float dc = dv[ll];
                float xc = xvv[ll];
                float du = dc * xc;
                PCHAIN_E16(dc);
                float y = 0.f;
#pragma unroll
                for (int q = 0; q < 4; q++) {
                    float4 v = *(const float4*)&bsm[(s * CL + ll) * NST + q * 4];
                    float4 w = *(const float4*)&csm[(s * CL + ll) * NST + q * 4];
                    h[q * 4 + 0] = fmaf(e_[q * 4 + 0], h[q * 4 + 0], du * v.x);
                    h[q * 4 + 1] = fmaf(e_[q * 4 + 1], h[q * 4 + 1], du * v.y);
                    h[q * 4 + 2] = fmaf(e_[q * 4 + 2], h[q * 4 + 2], du * v.z);
                    h[q * 4 + 3] = fmaf(e_[q * 4 + 3], h[q * 4 + 3], du * v.w);
                    y = fmaf(h[q * 4 + 0], w.x, y);
                    y = fmaf(h[q * 4 + 1], w.y, y);
                    y = fmaf(h[q * 4 + 2], w.z, y);
                    y = fmaf(h[q * 4 + 3], w.w, y);
                }
                out[idx] = fmaf(xc, Dd, y);
                idx += DI;
            }
        } else {
            for (int ll = 0; ll < CL; ll++) {
                float dc = dv[ll];
                float xc = xvv[ll];
                float du = dc * xc;
                float y = 0.f;
#pragma unroll
                for (int q = 0; q < 4; q++) {
                    float4 v = *(const float4*)&bsm[(s * CL + ll) * NST + q * 4];
                    float4 w = *(const float4*)&csm[(s * CL + ll) * NST + q * 4];
                    h[q * 4 + 0] = fmaf(__expf(dc * A[q * 4 + 0]), h[q * 4 + 0], du * v.x);
                    h[q * 4 + 1] = fmaf(__expf(dc * A[q * 4 + 1]), h[q * 4 + 1], du * v.y);
                    h[q * 4 + 2] = fmaf(__expf(dc * A[q * 4 + 2]), h[q * 4 + 2], du * v.z);
                    h[q * 4 + 3] = fmaf(__expf(dc * A[q * 4 + 3]), h[q * 4 + 3], du * v.w);
                    y = fmaf(h[q * 4 + 0], w.x, y);
                    y = fmaf(h[q * 4 + 1], w.y, y);
                    y = fmaf(h[q * 4 + 2], w.z, y);
                    y = fmaf(h[q * 4 + 3], w.w, y);
                }
                out[idx] = fmaf(xc, Dd, y);
                idx += DI;
            }
        }
    }
}

extern "C" void kernel_launch(void* const* d_in, const int* in_sizes, int n_in,
                              void* d_out, int out_size, void* d_ws, size_t ws_size,
                              hipStream_t stream) {
    const float* x    = (const float*)d_in[0];
    const float* Wx   = (const float*)d_in[1];
    const float* Wdt  = (const float*)d_in[2];
    const float* bdt  = (const float*)d_in[3];
    const float* Alog = (const float*)d_in[4];
    const float* Dp   = (const float*)d_in[5];
    float* out = (float*)d_out;
    float* ws = (float*)d_ws;
    float* xdbl  = ws + WS_XDBL;
    float* partb = ws + WS_PART;
    float* hloc  = ws + WS_HLOC;   // overlays partials (disjoint lifetime)
    float* dsumb = ws + WS_DSUM;
    float* hent  = ws + WS_HENT;
    float* wdtT  = ws + WS_WDTT;

    gemm_xproj_part<<<dim3(NROW / 128, SPLITK), 512, 0, stream>>>(x, Wx, partb);
    xproj_reduce_wt<<<dim3(512), 256, 0, stream>>>(partb, xdbl, Wdt, wdtT);
    gemm_dt_scan<<<dim3(DI / 256, NCH, BATCH), 256, 0, stream>>>(x, xdbl, wdtT, bdt, Alog,
                                                                 out, hloc, dsumb);
    scan_prefix<<<dim3(BATCH * DI * NST / 256), 256, 0, stream>>>(Alog, hloc, dsumb, hent);
    scan_out<<<dim3(DI / 256, NCH, BATCH), 256, 0, stream>>>(x, xdbl, Alog, Dp, hent, out);
}

// Round 9
// 182.162 us; speedup vs baseline: 1.1835x; 1.1461x over previous
//
#include <hip/hip_runtime.h>

#define BATCH 2
#define L_SEQ 2048
#define DI 2048
#define NROW (BATCH * L_SEQ)   // 4096
#define E_DIM 96
#define RNK 64                 // DT_RANK
#define NST 16                 // D_STATE
#define NCH 64                 // chunks
#define CL 32                  // chunk length (NCH*CL == L_SEQ)
#define SPLITK 16              // K1 split-K factor
#define KSL (DI / SPLITK)      // 128 k per split

// ---------------- workspace layout (floats) ---- (round-4 proven) ----
// xdbl  : [NROW][96]                               393216
// partials : [SPLITK][NROW][96]  6291456  (K1 -> reduce, then dead)
//   hloc : [B][NCH][NST][DI]     4194304  (overlays partials; C -> S2)
//   dsum : [B][NCH][DI]           262144  (overlays partials; C -> S2)
// hent  : [B][NCH][NST][DI]      4194304  (S2 -> S3)
//   WdtT : [RNK][DI]              131072  (overlays hent head; K1b -> C, dead before S2)
#define WS_XDBL 0
#define WS_PART 393216
#define WS_HLOC 393216
#define WS_DSUM (393216 + 4194304)
#define WS_HENT (393216 + 6291456)
#define WS_WDTT (393216 + 6291456)   // proven overlap: C reads before S2 writes hent

__device__ __forceinline__ float softplusf(float z) {
    return fmaxf(z, 0.f) + __logf(1.f + __expf(-fabsf(z)));
}

// raw barrier: LDS-visibility only (lgkmcnt), does NOT drain vmcnt.
__device__ __forceinline__ void barrier_lds() {
    asm volatile("s_waitcnt lgkmcnt(0)" ::: "memory");
    __builtin_amdgcn_s_barrier();
}

// power chain: e_[n] = p1^(n+1), 1 exp + 15 mul (valid when A[n]==(n+1)*A0)
#define PCHAIN_E16(DCV) \
    float p1 = __expf((DCV) * A0); \
    float p2 = p1 * p1, p3 = p2 * p1, p4 = p2 * p2, p5 = p4 * p1; \
    float p6 = p3 * p3, p7 = p4 * p3, p8 = p4 * p4; \
    float e_[16] = {p1, p2, p3, p4, p5, p6, p7, p8, \
                    p8 * p1, p5 * p5, p8 * p3, p6 * p6, \
                    p8 * p5, p7 * p7, p8 * p7, p8 * p8};

// ===== K1a: partial[s] = x[:, ksl] @ W^T slice =====
// 512 threads, tile M=128 x N=96, k-step 32, KSL=128. grid (32, 16).
// M=128 halves W HBM traffic vs M=64 (passed r7+r8).
__global__ __launch_bounds__(512) void gemm_xproj_part(const float* __restrict__ x,
                                                       const float* __restrict__ Wx,
                                                       float* __restrict__ part) {
    __shared__ float xs[32][132];   // [k][row 0..127], pitch 528B (16B aligned)
    __shared__ float wsh[32][100];  // [k][e]
    const int tid = threadIdx.x;
    const int r0 = blockIdx.x * 128;
    const int kbase0 = blockIdx.y * KSL;
    const int rg = tid >> 4;   // 32 groups of 4 rows
    const int cg = tid & 15;   // 16 groups of 6 cols

    float acc[4][6];
#pragma unroll
    for (int i = 0; i < 4; i++)
#pragma unroll
        for (int j = 0; j < 6; j++) acc[i][j] = 0.f;

    for (int kt = 0; kt < KSL / 32; kt++) {
        const int kb = kbase0 + kt * 32;
#pragma unroll
        for (int rep = 0; rep < 2; rep++) {
            int i = rep * 512 + tid;
            int row = i >> 3, kq = i & 7;
            float4 v = *(const float4*)&x[(long)(r0 + row) * DI + kb + kq * 4];
            xs[kq * 4 + 0][row] = v.x;
            xs[kq * 4 + 1][row] = v.y;
            xs[kq * 4 + 2][row] = v.z;
            xs[kq * 4 + 3][row] = v.w;
        }
        {
            int e = tid >> 3, kq = tid & 7;
            float4 v = *(const float4*)&Wx[(long)e * DI + kb + kq * 4];
            wsh[kq * 4 + 0][e] = v.x;
            wsh[kq * 4 + 1][e] = v.y;
            wsh[kq * 4 + 2][e] = v.z;
            wsh[kq * 4 + 3][e] = v.w;
        }
        if (tid < 256) {
            int i = 512 + tid;
            int e = i >> 3, kq = i & 7;
            float4 v = *(const float4*)&Wx[(long)e * DI + kb + kq * 4];
            wsh[kq * 4 + 0][e] = v.x;
            wsh[kq * 4 + 1][e] = v.y;
            wsh[kq * 4 + 2][e] = v.z;
            wsh[kq * 4 + 3][e] = v.w;
        }
        __syncthreads();
#pragma unroll 8
        for (int k = 0; k < 32; k++) {
            float4 xa = *(const float4*)&xs[k][rg * 4];   // b128 (16B aligned)
            float xr[4] = {xa.x, xa.y, xa.z, xa.w};
            float wr[6];
#pragma unroll
            for (int j = 0; j < 6; j++) wr[j] = wsh[k][cg * 6 + j];
#pragma unroll
            for (int i = 0; i < 4; i++)
#pragma unroll
                for (int j = 0; j < 6; j++) acc[i][j] = fmaf(xr[i], wr[j], acc[i][j]);
        }
        __syncthreads();
    }
    const long sbase = (long)blockIdx.y * NROW * E_DIM;
#pragma unroll
    for (int i = 0; i < 4; i++) {
        long rowb = sbase + (long)(r0 + rg * 4 + i) * E_DIM + cg * 6;
#pragma unroll
        for (int j = 0; j < 6; j++) part[rowb + j] = acc[i][j];
    }
}

// ===== K1b: xdbl = sum over splits + WdtT transpose (proven) =====
__global__ __launch_bounds__(256) void xproj_reduce_wt(const float* __restrict__ part,
                                                       float* __restrict__ xdbl,
                                                       const float* __restrict__ Wdt,
                                                       float* __restrict__ wdtT) {
    if (blockIdx.x < 384) {
        const int i4 = blockIdx.x * 256 + threadIdx.x;
        const float4* p4 = (const float4*)part;
        float4 s = p4[i4];
#pragma unroll
        for (int sp = 1; sp < SPLITK; sp++) {
            float4 v = p4[(long)sp * (NROW * E_DIM / 4) + i4];
            s.x += v.x; s.y += v.y; s.z += v.z; s.w += v.w;
        }
        ((float4*)xdbl)[i4] = s;
    } else {
        const int t = (blockIdx.x - 384) * 256 + threadIdx.x;
        const int base = t * 4;
        const int r = base >> 11;
        const int d4 = base & (DI - 1);
        float4 o;
        o.x = Wdt[(long)(d4 + 0) * RNK + r];
        o.y = Wdt[(long)(d4 + 1) * RNK + r];
        o.z = Wdt[(long)(d4 + 2) * RNK + r];
        o.w = Wdt[(long)(d4 + 3) * RNK + r];
        *(float4*)&wdtT[base] = o;
    }
}

// ===== C: fused delta-GEMM + chunk-local scan (round-4 body + T14 dbuf) =====
// grid (8, 64, 2) = 1024 blocks, 256 threads, 39.9KB LDS -> 4 blocks/CU.
// kt=1 wt/dlt loaded to REGISTERS before GEMM-kt0 (latency hidden); x/A/b
// prefetch issued after GEMM-kt0 (lands under GEMM-kt1) to bound VGPR peak.
#define PW 260   // wt pitch (16B-aligned rows; proven layout)
#define PD 36    // dlb pitch
__global__ __launch_bounds__(256) void gemm_dt_scan(const float* __restrict__ x,
                                                    const float* __restrict__ xdbl,
                                                    const float* __restrict__ wdtT,
                                                    const float* __restrict__ b_dt,
                                                    const float* __restrict__ A_log,
                                                    float* __restrict__ delta,
                                                    float* __restrict__ hloc,
                                                    float* __restrict__ dsumb) {
    __shared__ float region[32 * PW + 32 * PD];   // GEMM staging; dtt overlay
    __shared__ float bsm[CL * NST];               // 2 KB B tile
    float* wt  = region;                 // [32][PW]  Wdt^T staging [k][col]
    float* dlb = region + 32 * PW;       // [32][PD]  dlt staging [k][row]
    float* dtt = region;                 // [32][256] delta tile (overlay, after GEMM)

    const int tid = threadIdx.x;
    const int d0 = blockIdx.x * 256;
    const int c = blockIdx.y;
    const int b = blockIdx.z;
    const int row0 = b * L_SEQ + c * CL;
    const int d = d0 + tid;
    const int rg = tid >> 6;   // 4 groups of 8 rows (wave-uniform)
    const int cg = tid & 63;   // 64 groups of 4 cols

    // B tile (rows row0..row0+31, xdbl cols 64..79)
    if (tid < 128) {
        int r = tid >> 2, q = tid & 3;
        ((float4*)bsm)[tid] = *(const float4*)&xdbl[(long)(row0 + r) * E_DIM + 64 + q * 4];
    }

    float acc[8][4];
#pragma unroll
    for (int i = 0; i < 8; i++)
#pragma unroll
        for (int j = 0; j < 4; j++) acc[i][j] = 0.f;

    // ---- stage kt0 directly (load->LDS) ----
#pragma unroll
    for (int rep = 0; rep < 8; rep++) {
        int i = rep * 256 + tid;
        int k = i >> 6, c4 = i & 63;
        *(float4*)&wt[k * PW + c4 * 4] =
            *(const float4*)&wdtT[(long)k * DI + d0 + c4 * 4];
    }
    {
        int r = tid >> 3, kq = tid & 7;
        float4 v = *(const float4*)&xdbl[(long)(row0 + r) * E_DIM + kq * 4];
        dlb[(kq * 4 + 0) * PD + r] = v.x;
        dlb[(kq * 4 + 1) * PD + r] = v.y;
        dlb[(kq * 4 + 2) * PD + r] = v.z;
        dlb[(kq * 4 + 3) * PD + r] = v.w;
    }
    // ---- issue kt1 into registers (younger than kt0's vmcnt waits) ----
    float4 wq[8];
#pragma unroll
    for (int rep = 0; rep < 8; rep++) {
        int i = rep * 256 + tid;
        int k = i >> 6, c4 = i & 63;
        wq[rep] = *(const float4*)&wdtT[(long)(32 + k) * DI + d0 + c4 * 4];
    }
    float4 dq;
    { int r = tid >> 3, kq = tid & 7;
      dq = *(const float4*)&xdbl[(long)(row0 + r) * E_DIM + 32 + kq * 4]; }

    barrier_lds();
    // ---- GEMM kt0 ----
#pragma unroll 8
    for (int k = 0; k < 32; k++) {
        float4 xa = *(const float4*)&dlb[k * PD + rg * 8];       // broadcast
        float4 xb = *(const float4*)&dlb[k * PD + rg * 8 + 4];   // broadcast
        float4 w4 = *(const float4*)&wt[k * PW + cg * 4];        // 16B stride
        float xr[8] = {xa.x, xa.y, xa.z, xa.w, xb.x, xb.y, xb.z, xb.w};
#pragma unroll
        for (int i = 0; i < 8; i++) {
            acc[i][0] = fmaf(xr[i], w4.x, acc[i][0]);
            acc[i][1] = fmaf(xr[i], w4.y, acc[i][1]);
            acc[i][2] = fmaf(xr[i], w4.z, acc[i][2]);
            acc[i][3] = fmaf(xr[i], w4.w, acc[i][3]);
        }
    }
    barrier_lds();
    // ---- write kt1 from registers (loads landed under GEMM kt0) ----
#pragma unroll
    for (int rep = 0; rep < 8; rep++) {
        int i = rep * 256 + tid;
        int k = i >> 6, c4 = i & 63;
        *(float4*)&wt[k * PW + c4 * 4] = wq[rep];
    }
    {
        int r = tid >> 3, kq = tid & 7;
        dlb[(kq * 4 + 0) * PD + r] = dq.x;
        dlb[(kq * 4 + 1) * PD + r] = dq.y;
        dlb[(kq * 4 + 2) * PD + r] = dq.z;
        dlb[(kq * 4 + 3) * PD + r] = dq.w;
    }
    // ---- prefetch x column + params (land under GEMM kt1) ----
    float xv[CL];
#pragma unroll
    for (int ll = 0; ll < CL; ll++)
        xv[ll] = x[(long)(row0 + ll) * DI + d];
    float4 av[4];
#pragma unroll
    for (int q = 0; q < 4; q++)
        av[q] = *(const float4*)&A_log[(long)d * NST + q * 4];
    float4 bb = *(const float4*)&b_dt[d0 + cg * 4];

    barrier_lds();
    // ---- GEMM kt1 ----
#pragma unroll 8
    for (int k = 0; k < 32; k++) {
        float4 xa = *(const float4*)&dlb[k * PD + rg * 8];
        float4 xb = *(const float4*)&dlb[k * PD + rg * 8 + 4];
        float4 w4 = *(const float4*)&wt[k * PW + cg * 4];
        float xr[8] = {xa.x, xa.y, xa.z, xa.w, xb.x, xb.y, xb.z, xb.w};
#pragma unroll
        for (int i = 0; i < 8; i++) {
            acc[i][0] = fmaf(xr[i], w4.x, acc[i][0]);
            acc[i][1] = fmaf(xr[i], w4.y, acc[i][1]);
            acc[i][2] = fmaf(xr[i], w4.z, acc[i][2]);
            acc[i][3] = fmaf(xr[i], w4.w, acc[i][3]);
        }
    }
    barrier_lds();   // all GEMM reads done: dtt overlay safe

    // epilogue: bias + softplus -> global delta (fire-and-forget) + LDS delta tile
#pragma unroll
    for (int i = 0; i < 8; i++) {
        int r = rg * 8 + i;
        float4 o;
        o.x = softplusf(acc[i][0] + bb.x);
        o.y = softplusf(acc[i][1] + bb.y);
        o.z = softplusf(acc[i][2] + bb.z);
        o.w = softplusf(acc[i][3] + bb.w);
        *(float4*)&delta[(long)(row0 + r) * DI + d0 + cg * 4] = o;
        *(float4*)&dtt[r * 256 + cg * 4] = o;
    }

    float A[16];
#pragma unroll
    for (int q = 0; q < 4; q++) {
        A[q * 4 + 0] = -__expf(av[q].x);
        A[q * 4 + 1] = -__expf(av[q].y);
        A[q * 4 + 2] = -__expf(av[q].z);
        A[q * 4 + 3] = -__expf(av[q].w);
    }
    const float A0 = A[0];
    bool fast = true;
#pragma unroll
    for (int n = 1; n < 16; n++)
        fast = fast && (fabsf(A[n] - (float)(n + 1) * A0) <= 1e-4f * (float)(n + 1));
    barrier_lds();   // dtt visible

    float h[16];
#pragma unroll
    for (int n = 0; n < 16; n++) h[n] = 0.f;
    float dsum = 0.f;
    if (fast) {
        for (int ll = 0; ll < CL; ll++) {
            float dc = dtt[ll * 256 + tid];
            float du = dc * xv[ll];
            PCHAIN_E16(dc);
#pragma unroll
            for (int q = 0; q < 4; q++) {
                float4 v = *(const float4*)&bsm[ll * NST + q * 4];   // broadcast
                h[q * 4 + 0] = fmaf(e_[q * 4 + 0], h[q * 4 + 0], du * v.x);
                h[q * 4 + 1] = fmaf(e_[q * 4 + 1], h[q * 4 + 1], du * v.y);
                h[q * 4 + 2] = fmaf(e_[q * 4 + 2], h[q * 4 + 2], du * v.z);
                h[q * 4 + 3] = fmaf(e_[q * 4 + 3], h[q * 4 + 3], du * v.w);
            }
            dsum += dc;
        }
    } else {
        for (int ll = 0; ll < CL; ll++) {
            float dc = dtt[ll * 256 + tid];
            float du = dc * xv[ll];
#pragma unroll
            for (int q = 0; q < 4; q++) {
                float4 v = *(const float4*)&bsm[ll * NST + q * 4];
                h[q * 4 + 0] = fmaf(__expf(dc * A[q * 4 + 0]), h[q * 4 + 0], du * v.x);
                h[q * 4 + 1] = fmaf(__expf(dc * A[q * 4 + 1]), h[q * 4 + 1], du * v.y);
                h[q * 4 + 2] = fmaf(__expf(dc * A[q * 4 + 2]), h[q * 4 + 2], du * v.z);
                h[q * 4 + 3] = fmaf(__expf(dc * A[q * 4 + 3]), h[q * 4 + 3], du * v.w);
            }
            dsum += dc;
        }
    }
    // hloc layout [b][c][n][d]: 16 coalesced scalar stores
    const long cb = (long)(b * NCH + c);
#pragma unroll
    for (int n = 0; n < 16; n++)
        hloc[(cb * NST + n) * DI + d] = h[n];
    dsumb[cb * DI + d] = dsum;
}

// ===== S2: prefix over chunks -> entry states (rolling 8-batch loads) =====
__global__ __launch_bounds__(256, 1) void scan_prefix(const float* __restrict__ A_log,
                                                      const float* __restrict__ hloc,
                                                      const float* __restrict__ dsumb,
                                                      float* __restrict__ hent) {
    const int gidx = blockIdx.x * 256 + threadIdx.x;   // 65536 items, d fastest
    const int d = gidx & (DI - 1);
    const int n = (gidx >> 11) & 15;
    const int b = gidx >> 15;
    const float An = -__expf(A_log[(long)d * NST + n]);
    const long hstr = (long)NST * DI;
    const long hbase = (long)b * NCH * hstr + (long)n * DI + d;
    const long dbase = (long)b * NCH * DI + d;

    float hl[8], ds8[8], hln[8], dsn[8];
#pragma unroll
    for (int j = 0; j < 8; j++) {
        hl[j]  = hloc[hbase + j * hstr];
        ds8[j] = dsumb[dbase + j * DI];
    }
    float hc = 0.f;
#pragma unroll
    for (int c8 = 0; c8 < NCH; c8 += 8) {
        if (c8 + 8 < NCH) {
#pragma unroll
            for (int j = 0; j < 8; j++) {
                hln[j] = hloc[hbase + (c8 + 8 + j) * hstr];
                dsn[j] = dsumb[dbase + (c8 + 8 + j) * DI];
            }
        }
#pragma unroll
        for (int j = 0; j < 8; j++) {
            hent[hbase + (c8 + j) * hstr] = hc;
            hc = fmaf(__expf(An * ds8[j]), hc, hl[j]);
        }
#pragma unroll
        for (int j = 0; j < 8; j++) { hl[j] = hln[j]; ds8[j] = dsn[j]; }
    }
}

// ===== S3: output pass — columns prefetched to REGISTERS (round-4 proven) =====
__global__ __launch_bounds__(256) void scan_out(const float* __restrict__ x,
                                                const float* __restrict__ xdbl,
                                                const float* __restrict__ A_log,
                                                const float* __restrict__ Dp,
                                                const float* __restrict__ hent,
                                                float* __restrict__ out) {
    __shared__ float bsm[CL * NST];
    __shared__ float csm[CL * NST];
    const int tid = threadIdx.x;
    const int d0 = blockIdx.x * 256;
    const int c = blockIdx.y;
    const int b = blockIdx.z;
    const int row0 = b * L_SEQ + c * CL;
    const int d = d0 + tid;

    {
        int i = tid & 127, r = i >> 2, q = i & 3;
        float4 v = *(const float4*)&xdbl[(long)(row0 + r) * E_DIM + 64 + ((tid >> 7) << 4) + q * 4];
        if (tid < 128) ((float4*)bsm)[i] = v;
        else           ((float4*)csm)[i] = v;
    }
    __syncthreads();   // only LDS staging outstanding; cheap drain

    // params first (oldest in vmcnt FIFO)
    float4 av[4];
#pragma unroll
    for (int q = 0; q < 4; q++)
        av[q] = *(const float4*)&A_log[(long)d * NST + q * 4];
    const long cb = (long)(b * NCH + c);
    float hv[16];
#pragma unroll
    for (int n = 0; n < 16; n++)
        hv[n] = hent[(cb * NST + n) * DI + d];
    const float Dd = Dp[d];

    // column prefetch: delta (in `out`) + x
    float dv[CL], xvv[CL];
#pragma unroll
    for (int ll = 0; ll < CL; ll++) {
        dv[ll] = out[(long)(row0 + ll) * DI + d];
        xvv[ll] = x[(long)(row0 + ll) * DI + d];
    }

    float A[16];
#pragma unroll
    for (int q = 0; q < 4; q++) {
        A[q * 4 + 0] = -__expf(av[q].x);
        A[q * 4 + 1] = -__expf(av[q].y);
        A[q * 4 + 2] = -__expf(av[q].z);
        A[q * 4 + 3] = -__expf(av[q].w);
    }
    const float A0 = A[0];
    bool fast = true;
#pragma unroll
    for (int n = 1; n < 16; n++)
        fast = fast && (fabsf(A[n] - (float)(n + 1) * A0) <= 1e-4f * (float)(n + 1));
    float h[16];
#pragma unroll
    for (int n = 0; n < 16; n++) h[n] = hv[n];

    long idx = (long)row0 * DI + d;
    if (fast) {
        for (int ll = 0; ll < CL; ll++) {
            float dc = dv[ll];
            float xc = xvv[ll];
            float du = dc * xc;
            PCHAIN_E16(dc);
            float y = 0.f;
#pragma unroll
            for (int q = 0; q < 4; q++) {
                float4 v = *(const float4*)&bsm[ll * NST + q * 4];
                float4 w = *(const float4*)&csm[ll * NST + q * 4];
                h[q * 4 + 0] = fmaf(e_[q * 4 + 0], h[q * 4 + 0], du * v.x);
                h[q * 4 + 1] = fmaf(e_[q * 4 + 1], h[q * 4 + 1], du * v.y);
                h[q * 4 + 2] = fmaf(e_[q * 4 + 2], h[q * 4 + 2], du * v.z);
                h[q * 4 + 3] = fmaf(e_[q * 4 + 3], h[q * 4 + 3], du * v.w);
                y = fmaf(h[q * 4 + 0], w.x, y);
                y = fmaf(h[q * 4 + 1], w.y, y);
                y = fmaf(h[q * 4 + 2], w.z, y);
                y = fmaf(h[q * 4 + 3], w.w, y);
            }
            out[idx] = fmaf(xc, Dd, y);
            idx += DI;
        }
    } else {
        for (int ll = 0; ll < CL; ll++) {
            float dc = dv[ll];
            float xc = xvv[ll];
            float du = dc * xc;
            float y = 0.f;
#pragma unroll
            for (int q = 0; q < 4; q++) {
                float4 v = *(const float4*)&bsm[ll * NST + q * 4];
                float4 w = *(const float4*)&csm[ll * NST + q * 4];
                h[q * 4 + 0] = fmaf(__expf(dc * A[q * 4 + 0]), h[q * 4 + 0], du * v.x);
                h[q * 4 + 1] = fmaf(__expf(dc * A[q * 4 + 1]), h[q * 4 + 1], du * v.y);
                h[q * 4 + 2] = fmaf(__expf(dc * A[q * 4 + 2]), h[q * 4 + 2], du * v.z);
                h[q * 4 + 3] = fmaf(__expf(dc * A[q * 4 + 3]), h[q * 4 + 3], du * v.w);
                y = fmaf(h[q * 4 + 0], w.x, y);
                y = fmaf(h[q * 4 + 1], w.y, y);
                y = fmaf(h[q * 4 + 2], w.z, y);
                y = fmaf(h[q * 4 + 3], w.w, y);
            }
            out[idx] = fmaf(xc, Dd, y);
            idx += DI;
        }
    }
}

extern "C" void kernel_launch(void* const* d_in, const int* in_sizes, int n_in,
                              void* d_out, int out_size, void* d_ws, size_t ws_size,
                              hipStream_t stream) {
    const float* x    = (const float*)d_in[0];
    const float* Wx   = (const float*)d_in[1];
    const float* Wdt  = (const float*)d_in[2];
    const float* bdt  = (const float*)d_in[3];
    const float* Alog = (const float*)d_in[4];
    const float* Dp   = (const float*)d_in[5];
    float* out = (float*)d_out;
    float* ws = (float*)d_ws;
    float* xdbl  = ws + WS_XDBL;
    float* partb = ws + WS_PART;
    float* hloc  = ws + WS_HLOC;   // overlays partials (disjoint lifetime)
    float* dsumb = ws + WS_DSUM;
    float* hent  = ws + WS_HENT;
    float* wdtT  = ws + WS_WDTT;   // overlays hent head (dead before S2 writes)

    gemm_xproj_part<<<dim3(NROW / 128, SPLITK), 512, 0, stream>>>(x, Wx, partb);
    xproj_reduce_wt<<<dim3(512), 256, 0, stream>>>(partb, xdbl, Wdt, wdtT);
    gemm_dt_scan<<<dim3(DI / 256, NCH, BATCH), 256, 0, stream>>>(x, xdbl, wdtT, bdt, Alog,
                                                                 out, hloc, dsumb);
    scan_prefix<<<dim3(BATCH * DI * NST / 256), 256, 0, stream>>>(Alog, hloc, dsumb, hent);
    scan_out<<<dim3(DI / 256, NCH, BATCH), 256, 0, stream>>>(x, xdbl, Alog, Dp, hent, out);
}